// Round 7
// baseline (6809.744 us; speedup 1.0000x reference)
//
#include <hip/hip_runtime.h>

// StoichNet fused forward — fp16 hi/lo split MFMA, direct-L2 B operands.
// N=262144 elems, C=65536 reactions, H=4 heads.
// DIMS = [328, 256, 256, 256, 256, 128, 128, 64], res layers at 0,4,6.

constexpr int NN  = 262144;
constexpr int CC  = 65536;
constexpr int TM  = 64;    // rows per block (4 waves, col-split)
constexpr int BLK = 256;

typedef _Float16 f16x8 __attribute__((ext_vector_type(8)));
typedef float    f32x4 __attribute__((ext_vector_type(4)));

// packed-weight geometry per (head, job): [ct][ks] frag = 2048B (1KB hi + 1KB lo)
constexpr size_t OFF_W0  = 0;
constexpr size_t OFF_RW0 = 360448;
constexpr size_t OFF_W1  = 720896;
constexpr size_t OFF_W2  = 983040;
constexpr size_t OFF_W3  = 1245184;
constexpr size_t OFF_W4  = 1507328;
constexpr size_t OFF_RW4 = 1638400;
constexpr size_t OFF_W5  = 1769472;
constexpr size_t OFF_W6  = 1835008;
constexpr size_t OFF_RW6 = 1867776;
constexpr size_t HSTRIDE = 1900544;

__device__ __forceinline__ unsigned fenc(float f) {
  unsigned u = __float_as_uint(f);
  return (u & 0x80000000u) ? ~u : (u | 0x80000000u);
}
__device__ __forceinline__ float fdec(unsigned u) {
  return (u & 0x80000000u) ? __uint_as_float(u & 0x7fffffffu)
                           : __uint_as_float(~u);
}

// ---------------- weight pre-pack (every launch) ----------------
__global__ __launch_bounds__(256) void pack_kernel(
    const float* __restrict__ w0, const float* __restrict__ rw0,
    const float* __restrict__ w1, const float* __restrict__ w2,
    const float* __restrict__ w3, const float* __restrict__ w4,
    const float* __restrict__ rw4, const float* __restrict__ w5,
    const float* __restrict__ w6, const float* __restrict__ rw6,
    char* __restrict__ packed)
{
  const int job = blockIdx.y, head = blockIdx.z;
  const float* src; int DIN, DOUT, NK; size_t off;
  switch (job) {
    case 0: src = w0;  DIN = 328; DOUT = 256; NK = 11; off = OFF_W0;  break;
    case 1: src = rw0; DIN = 328; DOUT = 256; NK = 11; off = OFF_RW0; break;
    case 2: src = w1;  DIN = 256; DOUT = 256; NK = 8;  off = OFF_W1;  break;
    case 3: src = w2;  DIN = 256; DOUT = 256; NK = 8;  off = OFF_W2;  break;
    case 4: src = w3;  DIN = 256; DOUT = 256; NK = 8;  off = OFF_W3;  break;
    case 5: src = w4;  DIN = 256; DOUT = 128; NK = 8;  off = OFF_W4;  break;
    case 6: src = rw4; DIN = 256; DOUT = 128; NK = 8;  off = OFF_RW4; break;
    case 7: src = w5;  DIN = 128; DOUT = 128; NK = 4;  off = OFF_W5;  break;
    case 8: src = w6;  DIN = 128; DOUT = 64;  NK = 4;  off = OFF_W6;  break;
    default: src = rw6; DIN = 128; DOUT = 64; NK = 4;  off = OFF_RW6; break;
  }
  const int nct = DOUT >> 4;
  const int tid = blockIdx.x * 256 + threadIdx.x;
  if (tid >= nct * NK * 64) return;
  const int l = tid & 63, fs = tid >> 6;
  const int ks = fs % NK, ct = fs / NK;
  const int o  = ct * 16 + (l & 15);
  const int kb = ks * 32 + (l >> 4) * 8;
  float a[8];
  if (kb < DIN) {
    const float* p = src + (size_t)head * DOUT * DIN + (size_t)o * DIN + kb;
#pragma unroll
    for (int j = 0; j < 8; ++j) a[j] = p[j];
  } else {
#pragma unroll
    for (int j = 0; j < 8; ++j) a[j] = 0.f;
  }
  f16x8 hi, lo;
#pragma unroll
  for (int j = 0; j < 8; ++j) {
    _Float16 h = (_Float16)a[j];
    hi[j] = h;
    lo[j] = (_Float16)(a[j] - (float)h);
  }
  char* dst = packed + (size_t)head * HSTRIDE + off + (size_t)fs * 2048 + l * 16;
  *(f16x8*)dst = hi;
  *(f16x8*)(dst + 1024) = lo;
}

// ---------------- MLP ----------------
#define MFMA16(A, B, C) __builtin_amdgcn_mfma_f32_16x16x32_f16((A), (B), (C), 0, 0, 0)

// A-plane swizzled offset: element (row, col) -> byte
// 16B chunk index = col>>3, swizzled with row&7; row stride 512B.
__device__ __forceinline__ int aoff(int row, int chunk) {
  return (row * 32 + (chunk ^ (row & 7))) * 16;
}

template<int NCT, int NK, bool GA>
__device__ __forceinline__ void sweep(
    const char* __restrict__ packB,
    const char* __restrict__ aH, const char* __restrict__ aL,
    const float* __restrict__ orig, const float* __restrict__ embed,
    const int* nrt, const int* ert,
    int lane, int wv, f32x4 acc[NCT / 4][4])
{
  constexpr int W = NCT / 4;
  const int m = lane & 15, q = lane >> 4;
#pragma unroll
  for (int ks = 0; ks < NK; ++ks) {
    f16x8 Ah[4], Al[4];
#pragma unroll
    for (int rt = 0; rt < 4; ++rt) {
      if constexpr (GA) {
        const int g = ks * 4 + q;
        float a[8];
        if (g <= 24) {
          const float* p = orig + (size_t)nrt[rt] * 200 + g * 8;
#pragma unroll
          for (int j = 0; j < 8; ++j) a[j] = p[j];
        } else if (g <= 40) {
          const float* p = embed + (size_t)ert[rt] * 128 + (g - 25) * 8;
#pragma unroll
          for (int j = 0; j < 8; ++j) a[j] = p[j];
        } else {
#pragma unroll
          for (int j = 0; j < 8; ++j) a[j] = 0.f;
        }
#pragma unroll
        for (int j = 0; j < 8; ++j) {
          _Float16 h = (_Float16)a[j];
          Ah[rt][j] = h;
          Al[rt][j] = (_Float16)(a[j] - (float)h);
        }
      } else {
        const int off = aoff(rt * 16 + m, ks * 4 + q);
        Ah[rt] = *(const f16x8*)(aH + off);
        Al[rt] = *(const f16x8*)(aL + off);
      }
    }
#pragma unroll
    for (int i = 0; i < W; ++i) {
      const char* f = packB + (size_t)((wv + i * 4) * NK + ks) * 2048 + lane * 16;
      const f16x8 Bh = *(const f16x8*)f;
      const f16x8 Bl = *(const f16x8*)(f + 1024);
#pragma unroll
      for (int rt = 0; rt < 4; ++rt) {
        acc[i][rt] = MFMA16(Ah[rt], Bh, acc[i][rt]);
        acc[i][rt] = MFMA16(Ah[rt], Bl, acc[i][rt]);
        acc[i][rt] = MFMA16(Al[rt], Bh, acc[i][rt]);
      }
    }
  }
}

// MODE: 0 = store relu(acc+b); 1 = prev + accr; 2 = relu(acc+b) + prev; 3 = relu(acc+b) + accr
template<int W, int MODE>
__device__ __forceinline__ void epilogue(
    f32x4 acc[W][4], f32x4 accr[W][4], const float* __restrict__ bias,
    char* aH, char* aL, int lane, int wv)
{
  const int m = lane & 15, q = lane >> 4;
#pragma unroll
  for (int i = 0; i < W; ++i) {
    const int col = (wv + i * 4) * 16 + m;
    const float b = (MODE == 1) ? 0.f : bias[col];
    const int cchunk = col >> 3, csub = (col & 7) * 2;
#pragma unroll
    for (int rt = 0; rt < 4; ++rt) {
#pragma unroll
      for (int jr = 0; jr < 4; ++jr) {
        const int row = rt * 16 + q * 4 + jr;
        const int off = aoff(row, cchunk) + csub;
        _Float16* ph = (_Float16*)(aH + off);
        _Float16* pl = (_Float16*)(aL + off);
        float v;
        if constexpr (MODE == 0)      v = fmaxf(acc[i][rt][jr] + b, 0.f);
        else if constexpr (MODE == 1) v = ((float)*ph + (float)*pl) + accr[i][rt][jr];
        else if constexpr (MODE == 2) v = fmaxf(acc[i][rt][jr] + b, 0.f) + ((float)*ph + (float)*pl);
        else                          v = fmaxf(acc[i][rt][jr] + b, 0.f) + accr[i][rt][jr];
        _Float16 h = (_Float16)v;
        *ph = h;
        *pl = (_Float16)(v - (float)h);
      }
    }
  }
}

__global__ __launch_bounds__(BLK, 2) void mlp_kernel(
    const float* __restrict__ orig, const int* __restrict__ ridx,
    const float* __restrict__ embed, const char* __restrict__ packed,
    const float* __restrict__ b0, const float* __restrict__ b1,
    const float* __restrict__ b2, const float* __restrict__ b3,
    const float* __restrict__ b4, const float* __restrict__ b5,
    const float* __restrict__ b6,
    const float* __restrict__ wout, const float* __restrict__ bout,
    float* __restrict__ gate, unsigned* __restrict__ mmax)
{
  extern __shared__ char smem[];
  char*  aH    = smem;                       // [64][256] f16, swizzled
  char*  aL    = smem + 32768;
  float* gpart = (float*)(smem + 65536);     // [4][64]
  const int t = threadIdx.x, lane = t & 63, wv = t >> 6;
  const int m = lane & 15, q = lane >> 4;
  const int n0 = blockIdx.x * TM;
  int nrt[4], ert[4];
#pragma unroll
  for (int rt = 0; rt < 4; ++rt) {
    nrt[rt] = n0 + rt * 16 + m;
    ert[rt] = ridx[nrt[rt]];
  }
  const f32x4 Z4 = {0.f, 0.f, 0.f, 0.f};

#pragma unroll 1
  for (int head = 0; head < 4; ++head) {
    const char* pk = packed + (size_t)head * HSTRIDE;
    // ---- L0 (328 -> 256, linear res via store-then-add) ----
    {
      f32x4 acc[4][4];
#pragma unroll
      for (int i = 0; i < 4; ++i)
#pragma unroll
        for (int r = 0; r < 4; ++r) acc[i][r] = Z4;
      sweep<16, 11, true>(pk + OFF_W0, aH, aL, orig, embed, nrt, ert, lane, wv, acc);
      epilogue<4, 0>(acc, acc, b0 + head * 256, aH, aL, lane, wv);
#pragma unroll
      for (int i = 0; i < 4; ++i)
#pragma unroll
        for (int r = 0; r < 4; ++r) acc[i][r] = Z4;
      sweep<16, 11, true>(pk + OFF_RW0, aH, aL, orig, embed, nrt, ert, lane, wv, acc);
      epilogue<4, 1>(acc, acc, b0 + head * 256, aH, aL, lane, wv);
      __syncthreads();
    }
    // ---- L1..L3 (256 -> 256, identity res) ----
    {
      f32x4 acc[4][4];
#pragma unroll
      for (int i = 0; i < 4; ++i)
#pragma unroll
        for (int r = 0; r < 4; ++r) acc[i][r] = Z4;
      sweep<16, 8, false>(pk + OFF_W1, aH, aL, orig, embed, nrt, ert, lane, wv, acc);
      __syncthreads();
      epilogue<4, 2>(acc, acc, b1 + head * 256, aH, aL, lane, wv);
      __syncthreads();
    }
    {
      f32x4 acc[4][4];
#pragma unroll
      for (int i = 0; i < 4; ++i)
#pragma unroll
        for (int r = 0; r < 4; ++r) acc[i][r] = Z4;
      sweep<16, 8, false>(pk + OFF_W2, aH, aL, orig, embed, nrt, ert, lane, wv, acc);
      __syncthreads();
      epilogue<4, 2>(acc, acc, b2 + head * 256, aH, aL, lane, wv);
      __syncthreads();
    }
    {
      f32x4 acc[4][4];
#pragma unroll
      for (int i = 0; i < 4; ++i)
#pragma unroll
        for (int r = 0; r < 4; ++r) acc[i][r] = Z4;
      sweep<16, 8, false>(pk + OFF_W3, aH, aL, orig, embed, nrt, ert, lane, wv, acc);
      __syncthreads();
      epilogue<4, 2>(acc, acc, b3 + head * 256, aH, aL, lane, wv);
      __syncthreads();
    }
    // ---- L4 (256 -> 128, linear res) ----
    {
      f32x4 acc[2][4], accr[2][4];
#pragma unroll
      for (int i = 0; i < 2; ++i)
#pragma unroll
        for (int r = 0; r < 4; ++r) { acc[i][r] = Z4; accr[i][r] = Z4; }
      sweep<8, 8, false>(pk + OFF_W4,  aH, aL, orig, embed, nrt, ert, lane, wv, acc);
      sweep<8, 8, false>(pk + OFF_RW4, aH, aL, orig, embed, nrt, ert, lane, wv, accr);
      __syncthreads();
      epilogue<2, 3>(acc, accr, b4 + head * 128, aH, aL, lane, wv);
      __syncthreads();
    }
    // ---- L5 (128 -> 128, identity res) ----
    {
      f32x4 acc[2][4];
#pragma unroll
      for (int i = 0; i < 2; ++i)
#pragma unroll
        for (int r = 0; r < 4; ++r) acc[i][r] = Z4;
      sweep<8, 4, false>(pk + OFF_W5, aH, aL, orig, embed, nrt, ert, lane, wv, acc);
      __syncthreads();
      epilogue<2, 2>(acc, acc, b5 + head * 128, aH, aL, lane, wv);
      __syncthreads();
    }
    // ---- L6 (128 -> 64, linear res) + gate ----
    {
      f32x4 acc[1][4], accr[1][4];
#pragma unroll
      for (int r = 0; r < 4; ++r) { acc[0][r] = Z4; accr[0][r] = Z4; }
      sweep<4, 4, false>(pk + OFF_W6,  aH, aL, orig, embed, nrt, ert, lane, wv, acc);
      sweep<4, 4, false>(pk + OFF_RW6, aH, aL, orig, embed, nrt, ert, lane, wv, accr);
      __syncthreads();   // act reads done; prev-head gpart reads done
      const int col = wv * 16 + m;
      const float bb = b6[head * 64 + col];
      const float wo = wout[head * 64 + col];
#pragma unroll
      for (int rt = 0; rt < 4; ++rt) {
#pragma unroll
        for (int jr = 0; jr < 4; ++jr) {
          float v = fmaxf(acc[0][rt][jr] + bb, 0.f) + accr[0][rt][jr];
          float p = v * wo;
          p += __shfl_xor(p, 1);
          p += __shfl_xor(p, 2);
          p += __shfl_xor(p, 4);
          p += __shfl_xor(p, 8);
          if (m == 0) gpart[wv * 64 + rt * 16 + q * 4 + jr] = p;
        }
      }
      __syncthreads();
      if (t < 64) {
        float g = gpart[t] + gpart[64 + t] + gpart[128 + t] + gpart[192 + t]
                + bout[head];
        const int n = n0 + t;
        gate[(size_t)n * 4 + head] = g;
        atomicMax(mmax + (size_t)ridx[n] * 4 + head, fenc(g));
      }
      __syncthreads();
    }
  }
}

// ---------------- segment softmax tail ----------------
__global__ __launch_bounds__(BLK) void sm_pass2(
    const int* __restrict__ ridx, const unsigned* __restrict__ mmax,
    float* __restrict__ gate, float* __restrict__ denom)
{
  int tt = blockIdx.x * BLK + threadIdx.x;
  int n = tt >> 2, h = tt & 3;
  float g = gate[tt];
  int c = ridx[n];
  float mm = fdec(mmax[(size_t)c * 4 + h]);
  float ev = expf(g - mm);
  gate[tt] = ev;
  atomicAdd(denom + (size_t)c * 4 + h, ev);
}

__global__ __launch_bounds__(BLK) void sm_finalize(
    const int* __restrict__ ridx, const float* __restrict__ gate,
    const float* __restrict__ denom, float* __restrict__ out)
{
  int n = blockIdx.x * BLK + threadIdx.x;
  float4 e4 = *(const float4*)(gate + (size_t)n * 4);
  int c = ridx[n];
  float4 d4 = *(const float4*)(denom + (size_t)c * 4);
  out[n] = 0.25f * (e4.x / (d4.x + 1e-13f) + e4.y / (d4.y + 1e-13f) +
                    e4.z / (d4.z + 1e-13f) + e4.w / (d4.w + 1e-13f));
}

extern "C" void kernel_launch(void* const* d_in, const int* in_sizes, int n_in,
                              void* d_out, int out_size, void* d_ws, size_t ws_size,
                              hipStream_t stream) {
  (void)in_sizes; (void)n_in; (void)out_size; (void)ws_size;
  const float* orig  = (const float*)d_in[0];
  const int*   ridx  = (const int*)d_in[1];
  const float* embed = (const float*)d_in[2];
  const float* w0 = (const float*)d_in[3];  const float* b0 = (const float*)d_in[4];
  const float* w1 = (const float*)d_in[5];  const float* b1 = (const float*)d_in[6];
  const float* w2 = (const float*)d_in[7];  const float* b2 = (const float*)d_in[8];
  const float* w3 = (const float*)d_in[9];  const float* b3 = (const float*)d_in[10];
  const float* w4 = (const float*)d_in[11]; const float* b4 = (const float*)d_in[12];
  const float* w5 = (const float*)d_in[13]; const float* b5 = (const float*)d_in[14];
  const float* w6 = (const float*)d_in[15]; const float* b6 = (const float*)d_in[16];
  const float* rw0 = (const float*)d_in[17];
  const float* rw4 = (const float*)d_in[18];
  const float* rw6 = (const float*)d_in[19];
  const float* wout = (const float*)d_in[20];
  const float* bout = (const float*)d_in[21];

  // ws layout: gate 4MB | mmax 1MB | denom 1MB | packed weights ~7.3MB
  float*    gate   = (float*)d_ws;
  unsigned* mmax   = (unsigned*)((char*)d_ws + (size_t)4 * 1024 * 1024);
  float*    denom  = (float*)((char*)d_ws + (size_t)5 * 1024 * 1024);
  char*     packed = (char*)d_ws + (size_t)6 * 1024 * 1024;

  hipMemsetAsync(mmax, 0, (size_t)CC * 4 * sizeof(unsigned), stream);
  hipMemsetAsync(denom, 0, (size_t)CC * 4 * sizeof(float), stream);

  pack_kernel<<<dim3(44, 10, 4), 256, 0, stream>>>(
      w0, rw0, w1, w2, w3, w4, rw4, w5, w6, rw6, packed);

  hipFuncSetAttribute((const void*)mlp_kernel,
                      hipFuncAttributeMaxDynamicSharedMemorySize, 66560);
  mlp_kernel<<<NN / TM, BLK, 66560, stream>>>(
      orig, ridx, embed, packed,
      b0, b1, b2, b3, b4, b5, b6, wout, bout, gate, mmax);

  sm_pass2<<<NN * 4 / BLK, BLK, 0, stream>>>(ridx, mmax, gate, denom);
  sm_finalize<<<NN / BLK, BLK, 0, stream>>>(ridx, gate, denom, (float*)d_out);
}